// Round 7
// baseline (688.417 us; speedup 1.0000x reference)
//
#include <hip/hip_runtime.h>
#include <math.h>

#define Bn   64
#define Cin0 8
#define Vn   4096
#define V2n  1024
#define KK   8
#define DEG  32
#define FC1N 512
#define FC1IN 16384
#define BN_EPS 1e-5f

typedef float f32x4 __attribute__((ext_vector_type(4)));

struct Ptr8 { const float* p[8]; };

// ---------------- BatchNorm stats ----------------
__global__ void bn_stats_kernel(const float* __restrict__ x, float* __restrict__ stats) {
    int c = blockIdx.x;
    int chunk = blockIdx.y;
    const int per = (Bn * Vn) / 16;
    int base = chunk * per;
    float s = 0.f, s2 = 0.f;
    for (int i = threadIdx.x; i < per; i += 256) {
        int p = base + i;
        int b = p >> 12;
        int v = p & 4095;
        float val = x[((size_t)b * Cin0 + c) * Vn + v];
        s += val; s2 += val * val;
    }
    __shared__ float r1[256], r2[256];
    r1[threadIdx.x] = s; r2[threadIdx.x] = s2;
    __syncthreads();
    for (int off = 128; off > 0; off >>= 1) {
        if (threadIdx.x < off) {
            r1[threadIdx.x] += r1[threadIdx.x + off];
            r2[threadIdx.x] += r2[threadIdx.x + off];
        }
        __syncthreads();
    }
    if (threadIdx.x == 0) {
        atomicAdd(&stats[c], r1[0]);
        atomicAdd(&stats[8 + c], r2[0]);
    }
}

// ------------- BN apply + transpose (B,C,V) -> x0[v*512 + c*64 + b] -------------
__global__ void bn_apply_t_kernel(const float* __restrict__ x, const float* __restrict__ stats,
                                  float* __restrict__ x0) {
    int c = blockIdx.y;
    int v0 = blockIdx.x * 64;
    const float invN = 1.0f / (float)(Bn * Vn);
    float mean = stats[c] * invN;
    float var  = stats[8 + c] * invN - mean * mean;
    float sc = rsqrtf(var + BN_EPS);
    __shared__ float tile[64][65];
    int tx = threadIdx.x & 63;
    int ty = threadIdx.x >> 6;
    #pragma unroll
    for (int i = 0; i < 16; i++) {
        int b = i * 4 + ty;
        tile[b][tx] = x[((size_t)b * Cin0 + c) * Vn + v0 + tx];
    }
    __syncthreads();
    #pragma unroll
    for (int i = 0; i < 16; i++) {
        int vl = i * 4 + ty;
        float val = (tile[tx][vl] - mean) * sc;
        __builtin_nontemporal_store(val, x0 + (size_t)(v0 + vl) * 512 + c * 64 + tx);
    }
}

// ------------- SpMM, F-sliced with XCD-affinity swizzle -------------
// SLICES=4: V=4096, F=512 (graph1).  SLICES=16: V=1024, F=2048 (graph2).
// 8 rows/block, 32 lanes/row, 128-float (512B) slice per block.
template <int SLICES>
__global__ __launch_bounds__(256, 4) void spmm_kernel(
    const float* __restrict__ xin, const int* __restrict__ cols,
    const float* __restrict__ vals, const float* __restrict__ prev,
    float* __restrict__ y) {
    constexpr int F = SLICES * 128;
    int id = blockIdx.x;
    int s, g;
    if (SLICES == 4) {          // 4 slices -> 2 XCDs each (assume xcd = id&7)
        int xc = id & 7; s = xc >> 1; g = ((id >> 3) << 1) | (xc & 1);   // g in [0,512)
    } else {                    // 16 slices -> 2 slices per XCD
        int xc = id & 7; int q = id >> 3; s = (xc << 1) | (q & 1); g = q >> 1; // g in [0,128)
    }
    int r    = threadIdx.x >> 5;
    int lane = threadIdx.x & 31;
    int v = g * 8 + r;
    int fbase = s * 128 + lane * 4;
    __shared__ int   cs[8][DEG];
    __shared__ float vsh[8][DEG];
    {
        int e = threadIdx.x;                // 256 = 8 rows * 32 edges
        int vv = g * 8 + (e >> 5);
        cs[e >> 5][e & 31]  = cols[vv * DEG + (e & 31)];
        vsh[e >> 5][e & 31] = vals[vv * DEG + (e & 31)];
    }
    __syncthreads();
    float4 acc = make_float4(0.f, 0.f, 0.f, 0.f);
    #pragma unroll 8
    for (int e = 0; e < DEG; e++) {
        const float4 xv = *(const float4*)(xin + (size_t)cs[r][e] * F + fbase);
        float w = vsh[r][e];
        acc.x += w * xv.x; acc.y += w * xv.y; acc.z += w * xv.z; acc.w += w * xv.w;
    }
    size_t oi = (size_t)v * F + fbase;
    f32x4 o;
    if (prev) {
        f32x4 pv = __builtin_nontemporal_load((const f32x4*)(prev + oi));
        o.x = 2.f * acc.x - pv.x; o.y = 2.f * acc.y - pv.y;
        o.z = 2.f * acc.z - pv.z; o.w = 2.f * acc.w - pv.w;
    } else {
        o.x = acc.x; o.y = acc.y; o.z = acc.z; o.w = acc.w;
    }
    __builtin_nontemporal_store(o, (f32x4*)(y + oi));
}

// ------------- Dense combine: relu(xk@W^T+b) fused maxpool4 + transpose -------------
// MODE 0: 256 thr, JT=32 (whole W1), out[(vp*32+j)*64+b]
// MODE 1: 512 thr, JT=64 (whole W2), out[(j*256+vp)*64+b]
template <int CIN, int MODE, int NT>
__global__ void gemm_pool_kernel(Ptr8 xs, const float* __restrict__ W,
                                 const float* __restrict__ bias, float* __restrict__ out) {
    constexpr int IN = CIN * KK;              // 64 or 256
    constexpr int F  = CIN * 64;              // 512 or 2048
    constexpr int JT = (MODE == 0) ? 32 : 64;
    __shared__ float Ws[JT * IN];
    for (int i = threadIdx.x * 4; i < JT * IN; i += NT * 4)
        *(float4*)&Ws[i] = *(const float4*)&W[i];
    __syncthreads();
    int b  = threadIdx.x & 63;
    int jg = threadIdx.x >> 6;                // MODE0: 0..3, MODE1: 0..7
    int vp = blockIdx.x;
    float acc[4][8];
    #pragma unroll
    for (int vl = 0; vl < 4; vl++)
        #pragma unroll
        for (int jj = 0; jj < 8; jj++)
            acc[vl][jj] = bias[jg * 8 + jj];
    for (int c = 0; c < CIN; c++) {
        float xv[8][4];
        #pragma unroll
        for (int k = 0; k < 8; k++) {
            const float* __restrict__ xp = xs.p[k];
            #pragma unroll
            for (int vl = 0; vl < 4; vl++)
                xv[k][vl] = __builtin_nontemporal_load(xp + (size_t)(vp * 4 + vl) * F + c * 64 + b);
        }
        #pragma unroll
        for (int jj = 0; jj < 8; jj++) {
            int j = jg * 8 + jj;
            float4 w0 = *(const float4*)&Ws[j * IN + c * 8];
            float4 w1 = *(const float4*)&Ws[j * IN + c * 8 + 4];
            #pragma unroll
            for (int vl = 0; vl < 4; vl++)
                acc[vl][jj] += xv[0][vl] * w0.x + xv[1][vl] * w0.y + xv[2][vl] * w0.z + xv[3][vl] * w0.w
                             + xv[4][vl] * w1.x + xv[5][vl] * w1.y + xv[6][vl] * w1.z + xv[7][vl] * w1.w;
        }
    }
    #pragma unroll
    for (int jj = 0; jj < 8; jj++) {
        float m0 = fmaxf(fmaxf(acc[0][jj], acc[1][jj]), fmaxf(acc[2][jj], acc[3][jj]));
        m0 = fmaxf(m0, 0.0f);
        int j = jg * 8 + jj;
        if (MODE == 0)
            __builtin_nontemporal_store(m0, out + ((size_t)vp * 32 + j) * 64 + b);
        else
            __builtin_nontemporal_store(m0, out + ((size_t)j * 256 + vp) * 64 + b);
    }
}

// ------------- FC1 partial: scalar-pipe W loads (wave-uniform), no LDS -------------
// grid (16 ntiles, 64 kchunks); part[kc][n][b]
__global__ __launch_bounds__(256, 4) void fc1_partial_kernel(
    const float* __restrict__ A,      // [16384][64]
    const float* __restrict__ Wfc,    // [512][16384]
    float* __restrict__ part) {       // [64][512][64]
    int n0 = blockIdx.x * 32;
    int m0 = blockIdx.y * 256;
    int b  = threadIdx.x & 63;
    int ng = __builtin_amdgcn_readfirstlane(threadIdx.x >> 6);
    const float* __restrict__ Wr0 = Wfc + (size_t)(n0 + ng * 8) * FC1IN + m0;
    float acc[8];
    #pragma unroll
    for (int jn = 0; jn < 8; jn++) acc[jn] = 0.f;
    const float* __restrict__ Ap = A + (size_t)m0 * 64 + b;
    for (int mm = 0; mm < 256; mm += 4) {
        float a0 = Ap[(mm + 0) * 64];
        float a1 = Ap[(mm + 1) * 64];
        float a2 = Ap[(mm + 2) * 64];
        float a3 = Ap[(mm + 3) * 64];
        #pragma unroll
        for (int jn = 0; jn < 8; jn++) {
            const float* __restrict__ wr = Wr0 + (size_t)jn * FC1IN + mm;
            float w0 = wr[0], w1 = wr[1], w2 = wr[2], w3 = wr[3];
            acc[jn] += a0 * w0 + a1 * w1 + a2 * w2 + a3 * w3;
        }
    }
    #pragma unroll
    for (int jn = 0; jn < 8; jn++)
        __builtin_nontemporal_store(acc[jn],
            part + ((size_t)blockIdx.y * FC1N + n0 + ng * 8 + jn) * 64 + b);
}

// ------------- FC1 reduce + bias + sigmoid -------------
__global__ void fc1_reduce_kernel(const float* __restrict__ part, const float* __restrict__ bias,
                                  float* __restrict__ outA) {
    int idx = blockIdx.x * 256 + threadIdx.x;   // 32768 = 512*64
    int n = idx >> 6;
    float s = bias[n];
    #pragma unroll 8
    for (int mc = 0; mc < 64; mc++) s += part[(size_t)mc * 32768 + idx];
    outA[idx] = 1.0f / (1.0f + expf(-s));
}

// ------------- FC2 -------------
__global__ void fc2_kernel(const float* __restrict__ Afc, const float* __restrict__ W,
                           const float* __restrict__ bias, float* __restrict__ out) {
    int t = threadIdx.x;            // 256 = 64 b * 2 o * 2 halves
    int b = (t >> 1) & 63, o = t & 1, q = t >> 7;
    float s = 0.f;
    for (int n = q * 256; n < q * 256 + 256; n++)
        s += Afc[n * 64 + b] * W[o * 512 + n];
    __shared__ float red[256];
    red[t] = s;
    __syncthreads();
    if (q == 0)
        out[b * 2 + o] = red[t] + red[t + 128] + bias[o];
}

extern "C" void kernel_launch(void* const* d_in, const int* in_sizes, int n_in,
                              void* d_out, int out_size, void* d_ws, size_t ws_size,
                              hipStream_t stream) {
    const float* x     = (const float*)d_in[0];
    const int*   cols1 = (const int*)  d_in[2];
    const float* vals1 = (const float*)d_in[3];
    const int*   cols2 = (const int*)  d_in[5];
    const float* vals2 = (const float*)d_in[6];
    const float* w1    = (const float*)d_in[7];
    const float* b1    = (const float*)d_in[8];
    const float* w2    = (const float*)d_in[9];
    const float* b2    = (const float*)d_in[10];
    const float* fc1w  = (const float*)d_in[11];
    const float* fc1b  = (const float*)d_in[12];
    const float* fc2w  = (const float*)d_in[13];
    const float* fc2b  = (const float*)d_in[14];

    float* ws = (float*)d_ws;
    const size_t SLOT = (size_t)Vn * 512;   // 2,097,152 floats
    float* stats = ws;                      // 16 floats
    float* xs    = ws + 64;                 // 8 slots
    float* x02   = xs + 8 * SLOT;
    float* h2pT  = x02 + SLOT;              // [16384][64]
    // fc1 scratch reuses dead xs slots (graph data unused after gemm_pool<32,1>)
    float* fc1p  = xs;                      // [64][512][64] = exactly 1 SLOT
    float* fc1o  = xs + SLOT;               // 32768 floats

    (void)hipMemsetAsync(stats, 0, 16 * sizeof(float), stream);
    bn_stats_kernel<<<dim3(8, 16), 256, 0, stream>>>(x, stats);
    bn_apply_t_kernel<<<dim3(64, 8), 256, 0, stream>>>(x, stats, xs);

    // ---- graph conv 1: F=512, 4 slices x 512 rowgroups = 2048 blocks ----
    for (int k = 1; k < 8; k++)
        spmm_kernel<4><<<dim3(2048), 256, 0, stream>>>(
            xs + (size_t)(k - 1) * SLOT, cols1, vals1,
            (k >= 2) ? xs + (size_t)(k - 2) * SLOT : nullptr,
            xs + (size_t)k * SLOT);
    Ptr8 p1;
    for (int k = 0; k < 8; k++) p1.p[k] = xs + (size_t)k * SLOT;
    gemm_pool_kernel<8, 0, 256><<<dim3(1024), 256, 0, stream>>>(p1, w1, b1, x02);

    // ---- graph conv 2: F=2048, 16 slices x 128 rowgroups = 2048 blocks ----
    Ptr8 p2;
    p2.p[0] = x02;
    for (int k = 1; k < 8; k++) p2.p[k] = xs + (size_t)(k - 1) * SLOT;
    for (int k = 1; k < 8; k++)
        spmm_kernel<16><<<dim3(2048), 256, 0, stream>>>(
            p2.p[k - 1], cols2, vals2,
            (k >= 2) ? p2.p[k - 2] : nullptr,
            (float*)p2.p[k]);
    gemm_pool_kernel<32, 1, 512><<<dim3(256), 512, 0, stream>>>(p2, w2, b2, h2pT);

    // ---- FC head ----
    fc1_partial_kernel<<<dim3(16, 64), 256, 0, stream>>>(h2pT, fc1w, fc1p);
    fc1_reduce_kernel<<<dim3(128), 256, 0, stream>>>(fc1p, fc1b, fc1o);
    fc2_kernel<<<dim3(1), 256, 0, stream>>>(fc1o, fc2w, fc2b, (float*)d_out);
}

// Round 9
// 574.568 us; speedup vs baseline: 1.1981x; 1.1981x over previous
//
#include <hip/hip_runtime.h>
#include <math.h>

#define Bn   64
#define Cin0 8
#define Vn   4096
#define V2n  1024
#define KK   8
#define DEG  32
#define FC1N 512
#define FC1IN 16384
#define BN_EPS 1e-5f

typedef float f32x4 __attribute__((ext_vector_type(4)));

struct Ptr8 { const float* p[8]; };

// ---------------- BatchNorm stats ----------------
__global__ void bn_stats_kernel(const float* __restrict__ x, float* __restrict__ stats) {
    int c = blockIdx.x;
    int chunk = blockIdx.y;
    const int per = (Bn * Vn) / 16;
    int base = chunk * per;
    float s = 0.f, s2 = 0.f;
    for (int i = threadIdx.x; i < per; i += 256) {
        int p = base + i;
        int b = p >> 12;
        int v = p & 4095;
        float val = x[((size_t)b * Cin0 + c) * Vn + v];
        s += val; s2 += val * val;
    }
    __shared__ float r1[256], r2[256];
    r1[threadIdx.x] = s; r2[threadIdx.x] = s2;
    __syncthreads();
    for (int off = 128; off > 0; off >>= 1) {
        if (threadIdx.x < off) {
            r1[threadIdx.x] += r1[threadIdx.x + off];
            r2[threadIdx.x] += r2[threadIdx.x + off];
        }
        __syncthreads();
    }
    if (threadIdx.x == 0) {
        atomicAdd(&stats[c], r1[0]);
        atomicAdd(&stats[8 + c], r2[0]);
    }
}

// ------------- BN apply + transpose (B,C,V) -> x0[v*512 + c*64 + b] -------------
__global__ void bn_apply_t_kernel(const float* __restrict__ x, const float* __restrict__ stats,
                                  float* __restrict__ x0) {
    int c = blockIdx.y;
    int v0 = blockIdx.x * 64;
    const float invN = 1.0f / (float)(Bn * Vn);
    float mean = stats[c] * invN;
    float var  = stats[8 + c] * invN - mean * mean;
    float sc = rsqrtf(var + BN_EPS);
    __shared__ float tile[64][65];
    int tx = threadIdx.x & 63;
    int ty = threadIdx.x >> 6;
    #pragma unroll
    for (int i = 0; i < 16; i++) {
        int b = i * 4 + ty;
        tile[b][tx] = x[((size_t)b * Cin0 + c) * Vn + v0 + tx];
    }
    __syncthreads();
    #pragma unroll
    for (int i = 0; i < 16; i++) {
        int vl = i * 4 + ty;
        float val = (tile[tx][vl] - mean) * sc;   // tx = batch index here
        x0[(size_t)(v0 + vl) * 512 + c * 64 + tx] = val;
    }
}

// ------------- SpMM, F-sliced with XCD-affinity swizzle (NO nt anywhere) -------------
// SLICES=4: V=4096, F=512 (graph1).  SLICES=16: V=1024, F=2048 (graph2).
template <int SLICES>
__global__ __launch_bounds__(256, 4) void spmm_kernel(
    const float* __restrict__ xin, const int* __restrict__ cols,
    const float* __restrict__ vals, const float* __restrict__ prev,
    float* __restrict__ y) {
    constexpr int F = SLICES * 128;
    int id = blockIdx.x;
    int s, g;
    if (SLICES == 4) {          // 4 slices -> 2 XCDs each (assume xcd = id&7)
        int xc = id & 7; s = xc >> 1; g = ((id >> 3) << 1) | (xc & 1);   // g in [0,512)
    } else {                    // 16 slices -> 2 slices per XCD
        int xc = id & 7; int q = id >> 3; s = (xc << 1) | (q & 1); g = q >> 1; // g in [0,128)
    }
    int r    = threadIdx.x >> 5;
    int lane = threadIdx.x & 31;
    int v = g * 8 + r;
    int fbase = s * 128 + lane * 4;
    __shared__ int   cs[8][DEG];
    __shared__ float vsh[8][DEG];
    {
        int e = threadIdx.x;                // 256 = 8 rows * 32 edges
        int vv = g * 8 + (e >> 5);
        cs[e >> 5][e & 31]  = cols[vv * DEG + (e & 31)];
        vsh[e >> 5][e & 31] = vals[vv * DEG + (e & 31)];
    }
    __syncthreads();
    float4 acc = make_float4(0.f, 0.f, 0.f, 0.f);
    #pragma unroll 8
    for (int e = 0; e < DEG; e++) {
        const float4 xv = *(const float4*)(xin + (size_t)cs[r][e] * F + fbase);
        float w = vsh[r][e];
        acc.x += w * xv.x; acc.y += w * xv.y; acc.z += w * xv.z; acc.w += w * xv.w;
    }
    size_t oi = (size_t)v * F + fbase;
    float4 o;
    if (prev) {
        const float4 pv = *(const float4*)(prev + oi);
        o.x = 2.f * acc.x - pv.x; o.y = 2.f * acc.y - pv.y;
        o.z = 2.f * acc.z - pv.z; o.w = 2.f * acc.w - pv.w;
    } else {
        o = acc;
    }
    *(float4*)(y + oi) = o;
}

// ------------- Dense combine: relu(xk@W^T+b) fused maxpool4 + transpose -------------
// LDS-staged xk tile (each element loaded from global EXACTLY ONCE per block),
// W via wave-uniform scalar loads (jg readfirstlane'd -> s_load on scalar pipe).
// MODE 0: 256 thr, 32 j, out[(vp*32+j)*64+b]     (graph2 x0 layout)
// MODE 1: 512 thr, 64 j, out[(j*256+vp)*64+b]    (FC input A[m][b])
template <int CIN, int MODE, int NT>
__global__ __launch_bounds__(NT, 2) void gemm_pool_kernel(
    Ptr8 xs, const float* __restrict__ W,
    const float* __restrict__ bias, float* __restrict__ out) {
    constexpr int IN  = CIN * KK;             // 64 or 256
    constexpr int F   = CIN * 64;             // 512 or 2048
    constexpr int CCH = (MODE == 0) ? 4 : 8;  // c's per LDS chunk
    constexpr int NCH = CIN / CCH;            // 2 or 4 chunks
    __shared__ float lds[32 * CCH * 64];      // [k*4+vl][cc][b] : 32 or 64 KB
    int b  = threadIdx.x & 63;
    int jg = __builtin_amdgcn_readfirstlane(threadIdx.x >> 6); // wave-uniform j-group
    int vp = blockIdx.x;
    float acc[4][8] = {};
    for (int ch = 0; ch < NCH; ch++) {
        int c0 = ch * CCH;
        __syncthreads();
        // ---- stage chunk: 32 segments (k,vl) x CCH*64 contiguous floats ----
        constexpr int NF4 = 32 * CCH * 16;
        for (int i = threadIdx.x; i < NF4; i += NT) {
            int seg = i / (CCH * 16);
            int o4  = i - seg * (CCH * 16);
            int k = seg >> 2, vl = seg & 3;
            const float* gp = xs.p[k] + (size_t)(vp * 4 + vl) * F + c0 * 64 + o4 * 4;
            *(f32x4*)&lds[seg * (CCH * 64) + o4 * 4] = *(const f32x4*)gp;
        }
        __syncthreads();
        // ---- compute: per c, 32 LDS reads + 256 FMAs per thread ----
        for (int cc = 0; cc < CCH; cc++) {
            float xv[8][4];
            #pragma unroll
            for (int k = 0; k < 8; k++)
                #pragma unroll
                for (int vl = 0; vl < 4; vl++)
                    xv[k][vl] = lds[((k * 4 + vl) * CCH + cc) * 64 + b];
            int c = c0 + cc;
            #pragma unroll
            for (int jj = 0; jj < 8; jj++) {
                const float* __restrict__ wr = W + (size_t)(jg * 8 + jj) * IN + c * 8;
                #pragma unroll
                for (int k = 0; k < 8; k++) {
                    float w = wr[k];
                    acc[0][jj] += xv[k][0] * w;
                    acc[1][jj] += xv[k][1] * w;
                    acc[2][jj] += xv[k][2] * w;
                    acc[3][jj] += xv[k][3] * w;
                }
            }
        }
    }
    #pragma unroll
    for (int jj = 0; jj < 8; jj++) {
        int j = jg * 8 + jj;
        float m0 = fmaxf(fmaxf(acc[0][jj], acc[1][jj]), fmaxf(acc[2][jj], acc[3][jj]));
        m0 = fmaxf(m0 + bias[j], 0.0f);   // relu(max+bias) == max over vl of relu
        if (MODE == 0)
            out[((size_t)vp * 32 + j) * 64 + b] = m0;
        else
            out[((size_t)j * 256 + vp) * 64 + b] = m0;
    }
}

// ------------- FC1 partial: scalar-pipe W loads (wave-uniform), no LDS -------------
__global__ __launch_bounds__(256, 4) void fc1_partial_kernel(
    const float* __restrict__ A,      // [16384][64]
    const float* __restrict__ Wfc,    // [512][16384]
    float* __restrict__ part) {       // [64][512][64]
    int n0 = blockIdx.x * 32;
    int m0 = blockIdx.y * 256;
    int b  = threadIdx.x & 63;
    int ng = __builtin_amdgcn_readfirstlane(threadIdx.x >> 6);
    const float* __restrict__ Wr0 = Wfc + (size_t)(n0 + ng * 8) * FC1IN + m0;
    float acc[8];
    #pragma unroll
    for (int jn = 0; jn < 8; jn++) acc[jn] = 0.f;
    const float* __restrict__ Ap = A + (size_t)m0 * 64 + b;
    for (int mm = 0; mm < 256; mm += 4) {
        float a0 = Ap[(mm + 0) * 64];
        float a1 = Ap[(mm + 1) * 64];
        float a2 = Ap[(mm + 2) * 64];
        float a3 = Ap[(mm + 3) * 64];
        #pragma unroll
        for (int jn = 0; jn < 8; jn++) {
            const float* __restrict__ wr = Wr0 + (size_t)jn * FC1IN + mm;
            float w0 = wr[0], w1 = wr[1], w2 = wr[2], w3 = wr[3];
            acc[jn] += a0 * w0 + a1 * w1 + a2 * w2 + a3 * w3;
        }
    }
    #pragma unroll
    for (int jn = 0; jn < 8; jn++)
        part[((size_t)blockIdx.y * FC1N + n0 + ng * 8 + jn) * 64 + b] = acc[jn];
}

// ------------- FC1 reduce + bias + sigmoid -------------
__global__ void fc1_reduce_kernel(const float* __restrict__ part, const float* __restrict__ bias,
                                  float* __restrict__ outA) {
    int idx = blockIdx.x * 256 + threadIdx.x;   // 32768 = 512*64
    int n = idx >> 6;
    float s = bias[n];
    #pragma unroll 8
    for (int mc = 0; mc < 64; mc++) s += part[(size_t)mc * 32768 + idx];
    outA[idx] = 1.0f / (1.0f + expf(-s));
}

// ------------- FC2 -------------
__global__ void fc2_kernel(const float* __restrict__ Afc, const float* __restrict__ W,
                           const float* __restrict__ bias, float* __restrict__ out) {
    int t = threadIdx.x;            // 256 = 64 b * 2 o * 2 halves
    int b = (t >> 1) & 63, o = t & 1, q = t >> 7;
    float s = 0.f;
    for (int n = q * 256; n < q * 256 + 256; n++)
        s += Afc[n * 64 + b] * W[o * 512 + n];
    __shared__ float red[256];
    red[t] = s;
    __syncthreads();
    if (q == 0)
        out[b * 2 + o] = red[t] + red[t + 128] + bias[o];
}

extern "C" void kernel_launch(void* const* d_in, const int* in_sizes, int n_in,
                              void* d_out, int out_size, void* d_ws, size_t ws_size,
                              hipStream_t stream) {
    const float* x     = (const float*)d_in[0];
    const int*   cols1 = (const int*)  d_in[2];
    const float* vals1 = (const float*)d_in[3];
    const int*   cols2 = (const int*)  d_in[5];
    const float* vals2 = (const float*)d_in[6];
    const float* w1    = (const float*)d_in[7];
    const float* b1    = (const float*)d_in[8];
    const float* w2    = (const float*)d_in[9];
    const float* b2    = (const float*)d_in[10];
    const float* fc1w  = (const float*)d_in[11];
    const float* fc1b  = (const float*)d_in[12];
    const float* fc2w  = (const float*)d_in[13];
    const float* fc2b  = (const float*)d_in[14];

    float* ws = (float*)d_ws;
    const size_t SLOT = (size_t)Vn * 512;   // 2,097,152 floats
    float* stats = ws;                      // 16 floats
    float* xs    = ws + 64;                 // 8 slots
    float* x02   = xs + 8 * SLOT;
    float* h2pT  = x02 + SLOT;              // [16384][64]
    // fc1 scratch reuses dead xs slots (graph data unused after gemm_pool<32,1>)
    float* fc1p  = xs;                      // [64][512][64] = exactly 1 SLOT
    float* fc1o  = xs + SLOT;               // 32768 floats

    (void)hipMemsetAsync(stats, 0, 16 * sizeof(float), stream);
    bn_stats_kernel<<<dim3(8, 16), 256, 0, stream>>>(x, stats);
    bn_apply_t_kernel<<<dim3(64, 8), 256, 0, stream>>>(x, stats, xs);

    // ---- graph conv 1: F=512, 4 slices x 512 rowgroups = 2048 blocks ----
    for (int k = 1; k < 8; k++)
        spmm_kernel<4><<<dim3(2048), 256, 0, stream>>>(
            xs + (size_t)(k - 1) * SLOT, cols1, vals1,
            (k >= 2) ? xs + (size_t)(k - 2) * SLOT : nullptr,
            xs + (size_t)k * SLOT);
    Ptr8 p1;
    for (int k = 0; k < 8; k++) p1.p[k] = xs + (size_t)k * SLOT;
    gemm_pool_kernel<8, 0, 256><<<dim3(1024), 256, 0, stream>>>(p1, w1, b1, x02);

    // ---- graph conv 2: F=2048, 16 slices x 128 rowgroups = 2048 blocks ----
    Ptr8 p2;
    p2.p[0] = x02;
    for (int k = 1; k < 8; k++) p2.p[k] = xs + (size_t)(k - 1) * SLOT;
    for (int k = 1; k < 8; k++)
        spmm_kernel<16><<<dim3(2048), 256, 0, stream>>>(
            p2.p[k - 1], cols2, vals2,
            (k >= 2) ? p2.p[k - 2] : nullptr,
            (float*)p2.p[k]);
    gemm_pool_kernel<32, 1, 512><<<dim3(256), 512, 0, stream>>>(p2, w2, b2, h2pT);

    // ---- FC head ----
    fc1_partial_kernel<<<dim3(16, 64), 256, 0, stream>>>(h2pT, fc1w, fc1p);
    fc1_reduce_kernel<<<dim3(128), 256, 0, stream>>>(fc1p, fc1b, fc1o);
    fc2_kernel<<<dim3(1), 256, 0, stream>>>(fc1o, fc2w, fc2b, (float*)d_out);
}

// Round 11
// 483.338 us; speedup vs baseline: 1.4243x; 1.1887x over previous
//
#include <hip/hip_runtime.h>
#include <math.h>

#define Bn   64
#define Cin0 8
#define Vn   4096
#define V2n  1024
#define KK   8
#define DEG  32
#define FC1N 512
#define FC1IN 16384
#define BN_EPS 1e-5f

typedef float f32x4 __attribute__((ext_vector_type(4)));

struct Ptr8 { const float* p[8]; };

// ---------------- BatchNorm stats ----------------
__global__ void bn_stats_kernel(const float* __restrict__ x, float* __restrict__ stats) {
    int c = blockIdx.x;
    int chunk = blockIdx.y;
    const int per = (Bn * Vn) / 16;
    int base = chunk * per;
    float s = 0.f, s2 = 0.f;
    for (int i = threadIdx.x; i < per; i += 256) {
        int p = base + i;
        int b = p >> 12;
        int v = p & 4095;
        float val = x[((size_t)b * Cin0 + c) * Vn + v];
        s += val; s2 += val * val;
    }
    __shared__ float r1[256], r2[256];
    r1[threadIdx.x] = s; r2[threadIdx.x] = s2;
    __syncthreads();
    for (int off = 128; off > 0; off >>= 1) {
        if (threadIdx.x < off) {
            r1[threadIdx.x] += r1[threadIdx.x + off];
            r2[threadIdx.x] += r2[threadIdx.x + off];
        }
        __syncthreads();
    }
    if (threadIdx.x == 0) {
        atomicAdd(&stats[c], r1[0]);
        atomicAdd(&stats[8 + c], r2[0]);
    }
}

// ------------- BN apply + transpose (B,C,V) -> x0[v*512 + c*64 + b] -------------
__global__ void bn_apply_t_kernel(const float* __restrict__ x, const float* __restrict__ stats,
                                  float* __restrict__ x0) {
    int c = blockIdx.y;
    int v0 = blockIdx.x * 64;
    const float invN = 1.0f / (float)(Bn * Vn);
    float mean = stats[c] * invN;
    float var  = stats[8 + c] * invN - mean * mean;
    float sc = rsqrtf(var + BN_EPS);
    __shared__ float tile[64][65];
    int tx = threadIdx.x & 63;
    int ty = threadIdx.x >> 6;
    #pragma unroll
    for (int i = 0; i < 16; i++) {
        int b = i * 4 + ty;
        tile[b][tx] = x[((size_t)b * Cin0 + c) * Vn + v0 + tx];
    }
    __syncthreads();
    #pragma unroll
    for (int i = 0; i < 16; i++) {
        int vl = i * 4 + ty;
        float val = (tile[tx][vl] - mean) * sc;   // tx = batch index here
        x0[(size_t)(v0 + vl) * 512 + c * 64 + tx] = val;
    }
}

// ------------- SpMM, F-sliced with XCD-affinity swizzle -------------
// SLICES=4: V=4096, F=512 (graph1).  SLICES=16: V=1024, F=2048 (graph2).
template <int SLICES>
__global__ __launch_bounds__(256, 4) void spmm_kernel(
    const float* __restrict__ xin, const int* __restrict__ cols,
    const float* __restrict__ vals, const float* __restrict__ prev,
    float* __restrict__ y) {
    constexpr int F = SLICES * 128;
    int id = blockIdx.x;
    int s, g;
    if (SLICES == 4) {          // 4 slices -> 2 XCDs each (assume xcd = id&7)
        int xc = id & 7; s = xc >> 1; g = ((id >> 3) << 1) | (xc & 1);   // g in [0,512)
    } else {                    // 16 slices -> 2 slices per XCD
        int xc = id & 7; int q = id >> 3; s = (xc << 1) | (q & 1); g = q >> 1; // g in [0,128)
    }
    int r    = threadIdx.x >> 5;
    int lane = threadIdx.x & 31;
    int v = g * 8 + r;
    int fbase = s * 128 + lane * 4;
    __shared__ int   cs[8][DEG];
    __shared__ float vsh[8][DEG];
    {
        int e = threadIdx.x;                // 256 = 8 rows * 32 edges
        int vv = g * 8 + (e >> 5);
        cs[e >> 5][e & 31]  = cols[vv * DEG + (e & 31)];
        vsh[e >> 5][e & 31] = vals[vv * DEG + (e & 31)];
    }
    __syncthreads();
    float4 acc = make_float4(0.f, 0.f, 0.f, 0.f);
    #pragma unroll 8
    for (int e = 0; e < DEG; e++) {
        const float4 xv = *(const float4*)(xin + (size_t)cs[r][e] * F + fbase);
        float w = vsh[r][e];
        acc.x += w * xv.x; acc.y += w * xv.y; acc.z += w * xv.z; acc.w += w * xv.w;
    }
    size_t oi = (size_t)v * F + fbase;
    float4 o;
    if (prev) {
        const float4 pv = *(const float4*)(prev + oi);
        o.x = 2.f * acc.x - pv.x; o.y = 2.f * acc.y - pv.y;
        o.z = 2.f * acc.z - pv.z; o.w = 2.f * acc.w - pv.w;
    } else {
        o = acc;
    }
    *(float4*)(y + oi) = o;
}

// ------------- Dense combine: relu(xk@W^T+b) fused maxpool4 + transpose -------------
// LDS-staged xk tile; W via wave-uniform scalar loads.
// MODE 0: 256 thr, 32 j, out[(vp*32+j)*64+b]     (graph2 x0 layout)
// MODE 1: 512 thr, 64 j, out[(j*256+vp)*64+b]    (FC input A[m][b])
template <int CIN, int MODE, int NT>
__global__ __launch_bounds__(NT, 2) void gemm_pool_kernel(
    Ptr8 xs, const float* __restrict__ W,
    const float* __restrict__ bias, float* __restrict__ out) {
    constexpr int IN  = CIN * KK;             // 64 or 256
    constexpr int F   = CIN * 64;             // 512 or 2048
    constexpr int CCH = (MODE == 0) ? 4 : 8;  // c's per LDS chunk
    constexpr int NCH = CIN / CCH;            // 2 or 4 chunks
    __shared__ float lds[32 * CCH * 64];      // [k*4+vl][cc][b] : 32 or 64 KB
    int b  = threadIdx.x & 63;
    int jg = __builtin_amdgcn_readfirstlane(threadIdx.x >> 6); // wave-uniform j-group
    int vp = blockIdx.x;
    float acc[4][8] = {};
    for (int ch = 0; ch < NCH; ch++) {
        int c0 = ch * CCH;
        __syncthreads();
        constexpr int NF4 = 32 * CCH * 16;
        for (int i = threadIdx.x; i < NF4; i += NT) {
            int seg = i / (CCH * 16);
            int o4  = i - seg * (CCH * 16);
            int k = seg >> 2, vl = seg & 3;
            const float* gp = xs.p[k] + (size_t)(vp * 4 + vl) * F + c0 * 64 + o4 * 4;
            *(f32x4*)&lds[seg * (CCH * 64) + o4 * 4] = *(const f32x4*)gp;
        }
        __syncthreads();
        for (int cc = 0; cc < CCH; cc++) {
            float xv[8][4];
            #pragma unroll
            for (int k = 0; k < 8; k++)
                #pragma unroll
                for (int vl = 0; vl < 4; vl++)
                    xv[k][vl] = lds[((k * 4 + vl) * CCH + cc) * 64 + b];
            int c = c0 + cc;
            #pragma unroll
            for (int jj = 0; jj < 8; jj++) {
                const float* __restrict__ wr = W + (size_t)(jg * 8 + jj) * IN + c * 8;
                #pragma unroll
                for (int k = 0; k < 8; k++) {
                    float w = wr[k];
                    acc[0][jj] += xv[k][0] * w;
                    acc[1][jj] += xv[k][1] * w;
                    acc[2][jj] += xv[k][2] * w;
                    acc[3][jj] += xv[k][3] * w;
                }
            }
        }
    }
    #pragma unroll
    for (int jj = 0; jj < 8; jj++) {
        int j = jg * 8 + jj;
        float m0 = fmaxf(fmaxf(acc[0][jj], acc[1][jj]), fmaxf(acc[2][jj], acc[3][jj]));
        m0 = fmaxf(m0 + bias[j], 0.0f);
        if (MODE == 0)
            out[((size_t)vp * 32 + j) * 64 + b] = m0;
        else
            out[((size_t)j * 256 + vp) * 64 + b] = m0;
    }
}

// ------------- FC1 partial v3: A-tile AND W-tile in LDS, vector staging -------------
// grid (16 n-tiles of 32, 32 m-splits of 512); part[ms][n][b]
__global__ __launch_bounds__(256, 2) void fc1_partial_kernel(
    const float* __restrict__ A,      // [16384][64]
    const float* __restrict__ Wfc,    // [512][16384]
    float* __restrict__ part) {       // [32][512][64]
    __shared__ float Alds[128 * 64];  // 32 KB
    __shared__ float Wlds[32 * 128];  // 16 KB
    int n0 = blockIdx.x * 32;
    int m0 = blockIdx.y * 512;
    int b  = threadIdx.x & 63;
    int ng = threadIdx.x >> 6;        // 0..3
    float acc[8] = {};
    for (int ch = 0; ch < 4; ch++) {
        int mb = m0 + ch * 128;
        __syncthreads();
        // stage A[128][64]: 2048 float4, coalesced
        {
            const f32x4* __restrict__ src = (const f32x4*)(A + (size_t)mb * 64);
            f32x4* dst = (f32x4*)Alds;
            #pragma unroll
            for (int u = 0; u < 8; u++)
                dst[u * 256 + threadIdx.x] = src[u * 256 + threadIdx.x];
        }
        // stage W[32][128]: 8 threads/row, 64B contiguous per thread
        {
            int r = threadIdx.x >> 3;
            int c4 = (threadIdx.x & 7) * 4;
            const float* __restrict__ wr = Wfc + (size_t)(n0 + r) * FC1IN + mb;
            f32x4* dst = (f32x4*)&Wlds[r * 128];
            #pragma unroll
            for (int u = 0; u < 4; u++)
                dst[c4 + u] = *(const f32x4*)(wr + (c4 + u) * 4);
        }
        __syncthreads();
        // compute: per 4 m's: 4 A b32 reads + 8 W b128 broadcasts + 32 FMA
        for (int mm = 0; mm < 128; mm += 4) {
            float a0 = Alds[(mm + 0) * 64 + b];
            float a1 = Alds[(mm + 1) * 64 + b];
            float a2 = Alds[(mm + 2) * 64 + b];
            float a3 = Alds[(mm + 3) * 64 + b];
            #pragma unroll
            for (int jn = 0; jn < 8; jn++) {
                f32x4 w = *(const f32x4*)&Wlds[(ng * 8 + jn) * 128 + mm];
                acc[jn] += a0 * w.x + a1 * w.y + a2 * w.z + a3 * w.w;
            }
        }
    }
    #pragma unroll
    for (int jn = 0; jn < 8; jn++)
        part[((size_t)blockIdx.y * FC1N + n0 + ng * 8 + jn) * 64 + b] = acc[jn];
}

// ------------- FC1 reduce + bias + sigmoid -------------
__global__ void fc1_reduce_kernel(const float* __restrict__ part, const float* __restrict__ bias,
                                  float* __restrict__ outA) {
    int idx = blockIdx.x * 256 + threadIdx.x;   // 32768 = 512*64
    int n = idx >> 6;
    float s = bias[n];
    #pragma unroll 8
    for (int mc = 0; mc < 32; mc++) s += part[(size_t)mc * 32768 + idx];
    outA[idx] = 1.0f / (1.0f + expf(-s));
}

// ------------- FC2 -------------
__global__ void fc2_kernel(const float* __restrict__ Afc, const float* __restrict__ W,
                           const float* __restrict__ bias, float* __restrict__ out) {
    int t = threadIdx.x;            // 256 = 64 b * 2 o * 2 halves
    int b = (t >> 1) & 63, o = t & 1, q = t >> 7;
    float s = 0.f;
    for (int n = q * 256; n < q * 256 + 256; n++)
        s += Afc[n * 64 + b] * W[o * 512 + n];
    __shared__ float red[256];
    red[t] = s;
    __syncthreads();
    if (q == 0)
        out[b * 2 + o] = red[t] + red[t + 128] + bias[o];
}

extern "C" void kernel_launch(void* const* d_in, const int* in_sizes, int n_in,
                              void* d_out, int out_size, void* d_ws, size_t ws_size,
                              hipStream_t stream) {
    const float* x     = (const float*)d_in[0];
    const int*   cols1 = (const int*)  d_in[2];
    const float* vals1 = (const float*)d_in[3];
    const int*   cols2 = (const int*)  d_in[5];
    const float* vals2 = (const float*)d_in[6];
    const float* w1    = (const float*)d_in[7];
    const float* b1    = (const float*)d_in[8];
    const float* w2    = (const float*)d_in[9];
    const float* b2    = (const float*)d_in[10];
    const float* fc1w  = (const float*)d_in[11];
    const float* fc1b  = (const float*)d_in[12];
    const float* fc2w  = (const float*)d_in[13];
    const float* fc2b  = (const float*)d_in[14];

    float* ws = (float*)d_ws;
    const size_t SLOT = (size_t)Vn * 512;   // 2,097,152 floats
    float* stats = ws;                      // 16 floats
    float* xs    = ws + 64;                 // 8 slots
    float* x02   = xs + 8 * SLOT;
    float* h2pT  = x02 + SLOT;              // [16384][64]
    // fc1 scratch reuses dead xs slots (graph data unused after gemm_pool<32,1>)
    float* fc1p  = xs;                      // [32][512][64] = 1M floats
    float* fc1o  = xs + SLOT;               // 32768 floats

    (void)hipMemsetAsync(stats, 0, 16 * sizeof(float), stream);
    bn_stats_kernel<<<dim3(8, 16), 256, 0, stream>>>(x, stats);
    bn_apply_t_kernel<<<dim3(64, 8), 256, 0, stream>>>(x, stats, xs);

    // ---- graph conv 1: F=512, 4 slices x 512 rowgroups = 2048 blocks ----
    for (int k = 1; k < 8; k++)
        spmm_kernel<4><<<dim3(2048), 256, 0, stream>>>(
            xs + (size_t)(k - 1) * SLOT, cols1, vals1,
            (k >= 2) ? xs + (size_t)(k - 2) * SLOT : nullptr,
            xs + (size_t)k * SLOT);
    Ptr8 p1;
    for (int k = 0; k < 8; k++) p1.p[k] = xs + (size_t)k * SLOT;
    gemm_pool_kernel<8, 0, 256><<<dim3(1024), 256, 0, stream>>>(p1, w1, b1, x02);

    // ---- graph conv 2: F=2048, 16 slices x 128 rowgroups = 2048 blocks ----
    Ptr8 p2;
    p2.p[0] = x02;
    for (int k = 1; k < 8; k++) p2.p[k] = xs + (size_t)(k - 1) * SLOT;
    for (int k = 1; k < 8; k++)
        spmm_kernel<16><<<dim3(2048), 256, 0, stream>>>(
            p2.p[k - 1], cols2, vals2,
            (k >= 2) ? p2.p[k - 2] : nullptr,
            (float*)p2.p[k]);
    gemm_pool_kernel<32, 1, 512><<<dim3(256), 512, 0, stream>>>(p2, w2, b2, h2pT);

    // ---- FC head ----
    fc1_partial_kernel<<<dim3(16, 32), 256, 0, stream>>>(h2pT, fc1w, fc1p);
    fc1_reduce_kernel<<<dim3(128), 256, 0, stream>>>(fc1p, fc1b, fc1o);
    fc2_kernel<<<dim3(1), 256, 0, stream>>>(fc1o, fc2w, fc2b, (float*)d_out);
}

// Round 12
// 414.512 us; speedup vs baseline: 1.6608x; 1.1660x over previous
//
#include <hip/hip_runtime.h>
#include <math.h>

#define Bn   64
#define Cin0 8
#define Vn   4096
#define V2n  1024
#define KK   8
#define DEG  32
#define FC1N 512
#define FC1IN 16384
#define BN_EPS 1e-5f

typedef float f32x4 __attribute__((ext_vector_type(4)));

struct Ptr8 { const float* p[8]; };

// ---------------- BatchNorm stats ----------------
__global__ void bn_stats_kernel(const float* __restrict__ x, float* __restrict__ stats) {
    int c = blockIdx.x;
    int chunk = blockIdx.y;
    const int per = (Bn * Vn) / 16;
    int base = chunk * per;
    float s = 0.f, s2 = 0.f;
    for (int i = threadIdx.x; i < per; i += 256) {
        int p = base + i;
        int b = p >> 12;
        int v = p & 4095;
        float val = x[((size_t)b * Cin0 + c) * Vn + v];
        s += val; s2 += val * val;
    }
    __shared__ float r1[256], r2[256];
    r1[threadIdx.x] = s; r2[threadIdx.x] = s2;
    __syncthreads();
    for (int off = 128; off > 0; off >>= 1) {
        if (threadIdx.x < off) {
            r1[threadIdx.x] += r1[threadIdx.x + off];
            r2[threadIdx.x] += r2[threadIdx.x + off];
        }
        __syncthreads();
    }
    if (threadIdx.x == 0) {
        atomicAdd(&stats[c], r1[0]);
        atomicAdd(&stats[8 + c], r2[0]);
    }
}

// ------------- BN apply + transpose (B,C,V) -> x0[v*512 + c*64 + b] -------------
__global__ void bn_apply_t_kernel(const float* __restrict__ x, const float* __restrict__ stats,
                                  float* __restrict__ x0) {
    int c = blockIdx.y;
    int v0 = blockIdx.x * 64;
    const float invN = 1.0f / (float)(Bn * Vn);
    float mean = stats[c] * invN;
    float var  = stats[8 + c] * invN - mean * mean;
    float sc = rsqrtf(var + BN_EPS);
    __shared__ float tile[64][65];
    int tx = threadIdx.x & 63;
    int ty = threadIdx.x >> 6;
    #pragma unroll
    for (int i = 0; i < 16; i++) {
        int b = i * 4 + ty;
        tile[b][tx] = x[((size_t)b * Cin0 + c) * Vn + v0 + tx];
    }
    __syncthreads();
    #pragma unroll
    for (int i = 0; i < 16; i++) {
        int vl = i * 4 + ty;
        float val = (tile[tx][vl] - mean) * sc;   // tx = batch index here
        x0[(size_t)(v0 + vl) * 512 + c * 64 + tx] = val;
    }
}

// ------------- SpMM, F-sliced with XCD-affinity swizzle -------------
// SLICES=4: V=4096, F=512 (graph1).  SLICES=16: V=1024, F=2048 (graph2).
template <int SLICES>
__global__ __launch_bounds__(256, 4) void spmm_kernel(
    const float* __restrict__ xin, const int* __restrict__ cols,
    const float* __restrict__ vals, const float* __restrict__ prev,
    float* __restrict__ y) {
    constexpr int F = SLICES * 128;
    int id = blockIdx.x;
    int s, g;
    if (SLICES == 4) {          // 4 slices -> 2 XCDs each (assume xcd = id&7)
        int xc = id & 7; s = xc >> 1; g = ((id >> 3) << 1) | (xc & 1);   // g in [0,512)
    } else {                    // 16 slices -> 2 slices per XCD
        int xc = id & 7; int q = id >> 3; s = (xc << 1) | (q & 1); g = q >> 1; // g in [0,128)
    }
    int r    = threadIdx.x >> 5;
    int lane = threadIdx.x & 31;
    int v = g * 8 + r;
    int fbase = s * 128 + lane * 4;
    __shared__ int   cs[8][DEG];
    __shared__ float vsh[8][DEG];
    {
        int e = threadIdx.x;                // 256 = 8 rows * 32 edges
        int vv = g * 8 + (e >> 5);
        cs[e >> 5][e & 31]  = cols[vv * DEG + (e & 31)];
        vsh[e >> 5][e & 31] = vals[vv * DEG + (e & 31)];
    }
    __syncthreads();
    float4 acc = make_float4(0.f, 0.f, 0.f, 0.f);
    #pragma unroll 8
    for (int e = 0; e < DEG; e++) {
        const float4 xv = *(const float4*)(xin + (size_t)cs[r][e] * F + fbase);
        float w = vsh[r][e];
        acc.x += w * xv.x; acc.y += w * xv.y; acc.z += w * xv.z; acc.w += w * xv.w;
    }
    size_t oi = (size_t)v * F + fbase;
    float4 o;
    if (prev) {
        const float4 pv = *(const float4*)(prev + oi);
        o.x = 2.f * acc.x - pv.x; o.y = 2.f * acc.y - pv.y;
        o.z = 2.f * acc.z - pv.z; o.w = 2.f * acc.w - pv.w;
    } else {
        o = acc;
    }
    *(float4*)(y + oi) = o;
}

// ------------- Dense combine: relu(xk@W^T+b) fused maxpool4 + transpose -------------
// MODE 0: 256 thr, 32 j, out[(vp*32+j)*64+b]     (graph2 x0 layout)
// MODE 1: 512 thr, 64 j, out[(j*256+vp)*64+b]    (FC input A[m][b])
template <int CIN, int MODE, int NT>
__global__ __launch_bounds__(NT, 2) void gemm_pool_kernel(
    Ptr8 xs, const float* __restrict__ W,
    const float* __restrict__ bias, float* __restrict__ out) {
    constexpr int IN  = CIN * KK;             // 64 or 256
    constexpr int F   = CIN * 64;             // 512 or 2048
    constexpr int CCH = (MODE == 0) ? 4 : 8;  // c's per LDS chunk
    constexpr int NCH = CIN / CCH;            // 2 or 4 chunks
    __shared__ float lds[32 * CCH * 64];      // [k*4+vl][cc][b] : 32 or 64 KB
    int b  = threadIdx.x & 63;
    int jg = __builtin_amdgcn_readfirstlane(threadIdx.x >> 6); // wave-uniform j-group
    int vp = blockIdx.x;
    float acc[4][8] = {};
    for (int ch = 0; ch < NCH; ch++) {
        int c0 = ch * CCH;
        __syncthreads();
        constexpr int NF4 = 32 * CCH * 16;
        for (int i = threadIdx.x; i < NF4; i += NT) {
            int seg = i / (CCH * 16);
            int o4  = i - seg * (CCH * 16);
            int k = seg >> 2, vl = seg & 3;
            const float* gp = xs.p[k] + (size_t)(vp * 4 + vl) * F + c0 * 64 + o4 * 4;
            *(f32x4*)&lds[seg * (CCH * 64) + o4 * 4] = *(const f32x4*)gp;
        }
        __syncthreads();
        for (int cc = 0; cc < CCH; cc++) {
            float xv[8][4];
            #pragma unroll
            for (int k = 0; k < 8; k++)
                #pragma unroll
                for (int vl = 0; vl < 4; vl++)
                    xv[k][vl] = lds[((k * 4 + vl) * CCH + cc) * 64 + b];
            int c = c0 + cc;
            #pragma unroll
            for (int jj = 0; jj < 8; jj++) {
                const float* __restrict__ wr = W + (size_t)(jg * 8 + jj) * IN + c * 8;
                #pragma unroll
                for (int k = 0; k < 8; k++) {
                    float w = wr[k];
                    acc[0][jj] += xv[k][0] * w;
                    acc[1][jj] += xv[k][1] * w;
                    acc[2][jj] += xv[k][2] * w;
                    acc[3][jj] += xv[k][3] * w;
                }
            }
        }
    }
    #pragma unroll
    for (int jj = 0; jj < 8; jj++) {
        int j = jg * 8 + jj;
        float m0 = fmaxf(fmaxf(acc[0][jj], acc[1][jj]), fmaxf(acc[2][jj], acc[3][jj]));
        m0 = fmaxf(m0 + bias[j], 0.0f);
        if (MODE == 0)
            out[((size_t)vp * 32 + j) * 64 + b] = m0;
        else
            out[((size_t)j * 256 + vp) * 64 + b] = m0;
    }
}

// ------------- FC1 partial v3: A-tile AND W-tile in LDS, vector staging -------------
// grid (16 n-tiles of 32, 32 m-splits of 512); part[ms][n][b]
__global__ __launch_bounds__(256, 2) void fc1_partial_kernel(
    const float* __restrict__ A,      // [16384][64]
    const float* __restrict__ Wfc,    // [512][16384]
    float* __restrict__ part) {       // [32][512][64]
    __shared__ float Alds[128 * 64];  // 32 KB
    __shared__ float Wlds[32 * 128];  // 16 KB
    int n0 = blockIdx.x * 32;
    int m0 = blockIdx.y * 512;
    int b  = threadIdx.x & 63;
    int ng = threadIdx.x >> 6;        // 0..3
    float acc[8] = {};
    for (int ch = 0; ch < 4; ch++) {
        int mb = m0 + ch * 128;
        __syncthreads();
        {
            const f32x4* __restrict__ src = (const f32x4*)(A + (size_t)mb * 64);
            f32x4* dst = (f32x4*)Alds;
            #pragma unroll
            for (int u = 0; u < 8; u++)
                dst[u * 256 + threadIdx.x] = src[u * 256 + threadIdx.x];
        }
        {
            int r = threadIdx.x >> 3;
            int c4 = (threadIdx.x & 7) * 4;
            const float* __restrict__ wr = Wfc + (size_t)(n0 + r) * FC1IN + mb;
            f32x4* dst = (f32x4*)&Wlds[r * 128];
            #pragma unroll
            for (int u = 0; u < 4; u++)
                dst[c4 + u] = *(const f32x4*)(wr + (c4 + u) * 4);
        }
        __syncthreads();
        for (int mm = 0; mm < 128; mm += 4) {
            float a0 = Alds[(mm + 0) * 64 + b];
            float a1 = Alds[(mm + 1) * 64 + b];
            float a2 = Alds[(mm + 2) * 64 + b];
            float a3 = Alds[(mm + 3) * 64 + b];
            #pragma unroll
            for (int jn = 0; jn < 8; jn++) {
                f32x4 w = *(const f32x4*)&Wlds[(ng * 8 + jn) * 128 + mm];
                acc[jn] += a0 * w.x + a1 * w.y + a2 * w.z + a3 * w.w;
            }
        }
    }
    #pragma unroll
    for (int jn = 0; jn < 8; jn++)
        part[((size_t)blockIdx.y * FC1N + n0 + ng * 8 + jn) * 64 + b] = acc[jn];
}

// ------------- FC1 reduce + bias + sigmoid -------------
__global__ void fc1_reduce_kernel(const float* __restrict__ part, const float* __restrict__ bias,
                                  float* __restrict__ outA) {
    int idx = blockIdx.x * 256 + threadIdx.x;   // 32768 = 512*64
    int n = idx >> 6;
    float s = bias[n];
    #pragma unroll 8
    for (int mc = 0; mc < 32; mc++) s += part[(size_t)mc * 32768 + idx];
    outA[idx] = 1.0f / (1.0f + expf(-s));
}

// ------------- FC2 v2: 1024 threads, coalesced Afc reads, LDS W + tree reduce -------------
__global__ __launch_bounds__(1024) void fc2_kernel(const float* __restrict__ Afc,
                                                   const float* __restrict__ W,
                                                   const float* __restrict__ bias,
                                                   float* __restrict__ out) {
    __shared__ float Wl[1024];
    __shared__ float red[1024];
    int t = threadIdx.x;
    Wl[t] = W[t];                    // [2][512] = 1024 floats
    __syncthreads();
    int b = t & 63, o = (t >> 6) & 1, chunk = t >> 7;   // 8 chunks of 64 n
    const float* __restrict__ Ap = Afc + (size_t)(chunk * 64) * 64 + b;
    const float* __restrict__ Wp = Wl + o * 512 + chunk * 64;
    float s = 0.f;
    #pragma unroll
    for (int i = 0; i < 64; i++)
        s += Ap[i * 64] * Wp[i];     // lane=b consecutive -> coalesced; Wp wave-uniform
    red[t] = s;
    __syncthreads();
    if (t < 128) {                   // t = oo*64 + bb
        float acc = 0.f;
        #pragma unroll
        for (int c = 0; c < 8; c++) acc += red[c * 128 + t];
        out[(t & 63) * 2 + (t >> 6)] = acc + bias[t >> 6];
    }
}

extern "C" void kernel_launch(void* const* d_in, const int* in_sizes, int n_in,
                              void* d_out, int out_size, void* d_ws, size_t ws_size,
                              hipStream_t stream) {
    const float* x     = (const float*)d_in[0];
    const int*   cols1 = (const int*)  d_in[2];
    const float* vals1 = (const float*)d_in[3];
    const int*   cols2 = (const int*)  d_in[5];
    const float* vals2 = (const float*)d_in[6];
    const float* w1    = (const float*)d_in[7];
    const float* b1    = (const float*)d_in[8];
    const float* w2    = (const float*)d_in[9];
    const float* b2    = (const float*)d_in[10];
    const float* fc1w  = (const float*)d_in[11];
    const float* fc1b  = (const float*)d_in[12];
    const float* fc2w  = (const float*)d_in[13];
    const float* fc2b  = (const float*)d_in[14];

    float* ws = (float*)d_ws;
    const size_t SLOT = (size_t)Vn * 512;   // 2,097,152 floats
    float* stats = ws;                      // 16 floats
    float* xs    = ws + 64;                 // 8 slots
    float* x02   = xs + 8 * SLOT;
    float* h2pT  = x02 + SLOT;              // [16384][64]
    // fc1 scratch reuses dead xs slots (graph data unused after gemm_pool<32,1>)
    float* fc1p  = xs;                      // [32][512][64] = 1M floats
    float* fc1o  = xs + SLOT;               // 32768 floats

    (void)hipMemsetAsync(stats, 0, 16 * sizeof(float), stream);
    bn_stats_kernel<<<dim3(8, 16), 256, 0, stream>>>(x, stats);
    bn_apply_t_kernel<<<dim3(64, 8), 256, 0, stream>>>(x, stats, xs);

    // ---- graph conv 1: F=512, 4 slices x 512 rowgroups = 2048 blocks ----
    for (int k = 1; k < 8; k++)
        spmm_kernel<4><<<dim3(2048), 256, 0, stream>>>(
            xs + (size_t)(k - 1) * SLOT, cols1, vals1,
            (k >= 2) ? xs + (size_t)(k - 2) * SLOT : nullptr,
            xs + (size_t)k * SLOT);
    Ptr8 p1;
    for (int k = 0; k < 8; k++) p1.p[k] = xs + (size_t)k * SLOT;
    gemm_pool_kernel<8, 0, 256><<<dim3(1024), 256, 0, stream>>>(p1, w1, b1, x02);

    // ---- graph conv 2: F=2048, 16 slices x 128 rowgroups = 2048 blocks ----
    Ptr8 p2;
    p2.p[0] = x02;
    for (int k = 1; k < 8; k++) p2.p[k] = xs + (size_t)(k - 1) * SLOT;
    for (int k = 1; k < 8; k++)
        spmm_kernel<16><<<dim3(2048), 256, 0, stream>>>(
            p2.p[k - 1], cols2, vals2,
            (k >= 2) ? p2.p[k - 2] : nullptr,
            (float*)p2.p[k]);
    gemm_pool_kernel<32, 1, 512><<<dim3(256), 512, 0, stream>>>(p2, w2, b2, h2pT);

    // ---- FC head ----
    fc1_partial_kernel<<<dim3(16, 32), 256, 0, stream>>>(h2pT, fc1w, fc1p);
    fc1_reduce_kernel<<<dim3(128), 256, 0, stream>>>(fc1p, fc1b, fc1o);
    fc2_kernel<<<dim3(1), 1024, 0, stream>>>(fc1o, fc2w, fc2b, (float*)d_out);
}